// Round 1
// baseline (3905.866 us; speedup 1.0000x reference)
//
#include <hip/hip_runtime.h>

// LSTM B=1024 T=512 H=256 (input_size=1, output_size=1) on MI355X.
// R5: occupancy attack. R4 post-mortem: 2 waves/SIMD (256-reg/thread) left
// ~5000 cy/step of exposed latency (MfmaUtil 7%, VALUBusy 16%). Register-file
// weight capacity per CU is FIXED (512 KB) regardless of wave count, so:
// 1024 threads = 16 waves = 4 waves/SIMD, each wave owns hidden cols
// [16w,16w+16) and all four of its gate tiles:
//   i (Tn=w), f (Tn=16+w): register-resident (64 VGPR)
//   g (Tn=32+w):           LDS-resident (16 tiles = 128 KB, staged once)
//   o (Tn=48+w):           streamed from L2 via rotating 16-reg quarter
//                          buffer ob[4], reloaded per-kc with ~4-group
//                          prefetch distance (covers ~300-500 cy L2).
// Gate consts hoisted to 8 regs (no per-step gw/gb LDS), x prefetched one
// step ahead. Per-thread GATES halves (4 slots). ~128 VGPR/thread enforced
// by __launch_bounds__(1024,4). One __syncthreads per step. Epilogue:
// wave w shuffle-reduces batch row w.

#define HID 256
#define TT 512
#define BROWS 16
#define NBLK 64
#define THREADS 1024
#define HPAD 264

typedef float v4f __attribute__((ext_vector_type(4)));
typedef unsigned int v4u __attribute__((ext_vector_type(4)));
typedef __bf16 v8bf __attribute__((ext_vector_type(8)));

__device__ __forceinline__ unsigned short f2bf(float f) {
    unsigned int u = __builtin_bit_cast(unsigned int, f);
    u += 0x7fffu + ((u >> 16) & 1u);   // RNE
    return (unsigned short)(u >> 16);
}
__device__ __forceinline__ float bf2f(unsigned short s) {
    unsigned int u = ((unsigned int)s) << 16;
    return __builtin_bit_cast(float, u);
}
__device__ __forceinline__ float fsigmoid(float x) {
    float e = exp2f(x * -1.44269504f);
    return __builtin_amdgcn_rcpf(1.0f + e);
}
__device__ __forceinline__ float ftanh(float x) {
    float e = exp2f(x * 2.88539008f);
    return 1.0f - 2.0f * __builtin_amdgcn_rcpf(1.0f + e);
}

// W_hh fp32 [1024][256] -> bf16 fragment order:
// Wbf[((Tn*8+kc)*64+lane)*8 + j] = bf16(W_hh[16*Tn+(lane&15)][32*kc+(lane>>4)*8+j])
__global__ void wconv_kernel(const float* __restrict__ Whh,
                             unsigned short* __restrict__ Wbf) {
    int tid = blockIdx.x * blockDim.x + threadIdx.x;   // 0..32767
    int lane = tid & 63;
    int frag = tid >> 6;
    int Tn = frag >> 3;
    int kc = frag & 7;
    int n  = Tn * 16 + (lane & 15);
    int kb = kc * 32 + (lane >> 4) * 8;
    const float* src = Whh + (size_t)n * HID + kb;
    unsigned short* dst = Wbf + (size_t)tid * 8;
#pragma unroll
    for (int j = 0; j < 8; ++j) dst[j] = f2bf(src[j]);
}

__global__ __launch_bounds__(THREADS, 4)
void lstm_kernel(const float* __restrict__ x,
                 const float* __restrict__ W_ih,
                 const float* __restrict__ b_ih,
                 const float* __restrict__ b_hh,
                 const float* __restrict__ W_lin,
                 const float* __restrict__ b_lin,
                 const unsigned short* __restrict__ Wbf,
                 float* __restrict__ out) {
    __shared__ __align__(16) unsigned short Wlds[16 * 8 * 64 * 8];   // 128 KB (g tiles)
    __shared__ __align__(16) unsigned short hbuf[2][BROWS * HPAD];   // 16.9 KB

    const int tid  = threadIdx.x;
    const int lane = tid & 63;
    const int w    = tid >> 6;      // wave 0..15
    const int l4   = lane & 15;
    const int quad = lane >> 4;
    const int r0   = blockIdx.x * BROWS;
    const int col  = 16 * w + l4;   // this thread's hidden column

    // stage g-gate tile (Tn = 32+w) into LDS slot w
#pragma unroll
    for (int kc = 0; kc < 8; ++kc)
        *(v4u*)(Wlds + ((size_t)((w * 8 + kc) * 64 + lane)) * 8) =
            *(const v4u*)(Wbf + ((size_t)(((32 + w) * 8 + kc) * 64 + lane)) * 8);

    // h(0) = 0
    for (int i = tid; i < BROWS * HPAD; i += THREADS) hbuf[0][i] = 0;

    // register-resident i,f tiles (Tn = w, 16+w)
    v8bf wi[8], wf[8];
#pragma unroll
    for (int kc = 0; kc < 8; ++kc) {
        wi[kc] = __builtin_bit_cast(v8bf,
            *(const v4u*)(Wbf + ((size_t)((w * 8 + kc) * 64 + lane)) * 8));
        wf[kc] = __builtin_bit_cast(v8bf,
            *(const v4u*)(Wbf + ((size_t)(((16 + w) * 8 + kc) * 64 + lane)) * 8));
    }

    // per-thread gate constants (hoisted: no per-step LDS reads)
    const float cwi = W_ih[col],       cbi = b_ih[col]       + b_hh[col];
    const float cwf = W_ih[256 + col], cbf = b_ih[256 + col] + b_hh[256 + col];
    const float cwg = W_ih[512 + col], cbg = b_ih[512 + col] + b_hh[512 + col];
    const float cwo = W_ih[768 + col], cbo = b_ih[768 + col] + b_hh[768 + col];

    // o-gate L2 stream: rotating quarter buffer, prologue holds kc 0..3
    const v4u* optr = (const v4u*)(Wbf + ((size_t)((48 + w) * 8) * 64 + lane) * 8);
    v4u ob[4];
#pragma unroll
    for (int j = 0; j < 4; ++j) ob[j] = optr[j * 64];   // 64 v4u per kc chunk

    // x for t=0
    float xv[4];
#pragma unroll
    for (int r = 0; r < 4; ++r) xv[r] = x[(size_t)(r0 + quad * 4 + r) * TT];

    __syncthreads();

    float c_st[4] = {0.f, 0.f, 0.f, 0.f};
    int cur = 0;

    for (int t = 0; t < TT; ++t) {
        const unsigned short* hrow = hbuf[cur] + l4 * HPAD + quad * 8;
        unsigned short* hn = hbuf[cur ^ 1];

        v4f ai, af, ag, ao;
#pragma unroll
        for (int r = 0; r < 4; ++r) {
            ai[r] = xv[r] * cwi + cbi;
            af[r] = xv[r] * cwf + cbf;
            ag[r] = xv[r] * cwg + cbg;
            ao[r] = xv[r] * cwo + cbo;
        }

#pragma unroll
        for (int kc = 0; kc < 8; ++kc) {
            v8bf a = __builtin_bit_cast(v8bf, *(const v4u*)(hrow + kc * 32));
            v8bf g = __builtin_bit_cast(v8bf, *(const v4u*)(Wlds +
                        ((size_t)((w * 8 + kc) * 64 + lane)) * 8));
            ai = __builtin_amdgcn_mfma_f32_16x16x32_bf16(a, wi[kc], ai, 0, 0, 0);
            af = __builtin_amdgcn_mfma_f32_16x16x32_bf16(a, wf[kc], af, 0, 0, 0);
            ag = __builtin_amdgcn_mfma_f32_16x16x32_bf16(a, g, ag, 0, 0, 0);
            ao = __builtin_amdgcn_mfma_f32_16x16x32_bf16(a,
                     __builtin_bit_cast(v8bf, ob[kc & 3]), ao, 0, 0, 0);
            // reload just-consumed quarter: kc<4 -> kc+4 (this step),
            // kc>=4 -> kc-4 (next step). Prefetch distance ~4 kc-groups.
            ob[kc & 3] = optr[((kc + 4) & 7) * 64];
        }

        // prefetch x for t+1 (wraps harmlessly at the end)
        {
            int tn = (t + 1) & (TT - 1);
#pragma unroll
            for (int r = 0; r < 4; ++r)
                xv[r] = x[(size_t)(r0 + quad * 4 + r) * TT + tn];
        }

#pragma unroll
        for (int r = 0; r < 4; ++r) {
            float gi = fsigmoid(ai[r]);
            float gf = fsigmoid(af[r]);
            float gg = ftanh(ag[r]);
            float go = fsigmoid(ao[r]);
            float cn = gf * c_st[r] + gi * gg;
            c_st[r] = cn;
            hn[(quad * 4 + r) * HPAD + col] = f2bf(go * ftanh(cn));
        }

        cur ^= 1;
        __syncthreads();
    }

    // Epilogue: wave w reduces batch row w: out[b] = h . W_lin + b_lin
    float p = 0.f;
#pragma unroll
    for (int j = 0; j < 4; ++j) {
        int c = lane * 4 + j;
        p += bf2f(hbuf[cur][w * HPAD + c]) * W_lin[c];
    }
#pragma unroll
    for (int off = 32; off; off >>= 1) p += __shfl_down(p, off);
    if (lane == 0) out[r0 + w] = p + b_lin[0];
}

extern "C" void kernel_launch(void* const* d_in, const int* in_sizes, int n_in,
                              void* d_out, int out_size, void* d_ws, size_t ws_size,
                              hipStream_t stream) {
    const float* x     = (const float*)d_in[0];
    const float* W_ih  = (const float*)d_in[1];
    const float* W_hh  = (const float*)d_in[2];
    const float* b_ih  = (const float*)d_in[3];
    const float* b_hh  = (const float*)d_in[4];
    const float* W_lin = (const float*)d_in[5];
    const float* b_lin = (const float*)d_in[6];
    unsigned short* Wbf = (unsigned short*)d_ws;   // 512 KB

    wconv_kernel<<<128, 256, 0, stream>>>(W_hh, Wbf);
    lstm_kernel<<<NBLK, THREADS, 0, stream>>>(x, W_ih, b_ih, b_hh, W_lin, b_lin,
                                              Wbf, (float*)d_out);
}